// Round 1
// baseline (172.757 us; speedup 1.0000x reference)
//
#include <hip/hip_runtime.h>
#include <hip/hip_bf16.h>

#define S_LEN 3072
#define E_DIM 1280
#define NH 16
#define HD 80      // head dim
#define HDP 96     // head dim padded to 3*32 for K=32 MFMA chunks
#define QKV_N 3840

typedef unsigned short u16;
typedef __bf16 bf16x8 __attribute__((ext_vector_type(8)));
typedef float f32x4 __attribute__((ext_vector_type(4)));

__device__ __forceinline__ u16 bf16_bits(float f) {
  __hip_bfloat16 b = __float2bfloat16(f);
  return *reinterpret_cast<u16*>(&b);
}
__device__ __forceinline__ float bf16_to_f(u16 u) {
  unsigned int x = ((unsigned int)u) << 16;
  return __uint_as_float(x);
}

// ---------------- fp32 -> bf16 convert (vectorized) ----------------
__global__ __launch_bounds__(256) void f32_to_bf16_k(const float* __restrict__ src,
                                                     u16* __restrict__ dst, int n4) {
  int i = blockIdx.x * 256 + threadIdx.x;
  if (i >= n4) return;
  float4 v = reinterpret_cast<const float4*>(src)[i];
  ushort4 o;
  o.x = bf16_bits(v.x); o.y = bf16_bits(v.y); o.z = bf16_bits(v.z); o.w = bf16_bits(v.w);
  reinterpret_cast<ushort4*>(dst)[i] = o;
}

// ---------------- NT GEMM: C[M][N] = A[M][K] * B[N][K]^T + bias ----------------
// A,B bf16 row-major K-contig. 128x128 tile, 4 waves (2x2), each wave 64x64 = 4x4 frags.
template<int OUT_F32>
__global__ __launch_bounds__(256) void gemm_nt(const u16* __restrict__ A,
                                               const u16* __restrict__ B,
                                               const float* __restrict__ bias,
                                               void* __restrict__ Cout,
                                               int M, int N, int K) {
  __shared__ u16 As[128][40];  // +8 u16 pad (16B) to spread LDS banks
  __shared__ u16 Bs[128][40];
  const int t = threadIdx.x;
  const int lane = t & 63;
  const int wave = t >> 6;
  const int l15 = lane & 15, l4 = lane >> 4;
  const int wm = (wave >> 1) * 64, wn = (wave & 1) * 64;
  const int m0 = blockIdx.y * 128, n0 = blockIdx.x * 128;

  // staging: 512 chunks of 16B per tile; thread t does chunks t and t+256
  const int rA = t >> 2;          // row 0..63
  const int cA = (t & 3) * 8;     // col chunk (8 bf16)
  const u16* Ag0 = A + (size_t)(m0 + rA) * K + cA;
  const u16* Ag1 = A + (size_t)(m0 + rA + 64) * K + cA;
  const u16* Bg0 = B + (size_t)(n0 + rA) * K + cA;
  const u16* Bg1 = B + (size_t)(n0 + rA + 64) * K + cA;

  f32x4 acc[4][4] = {};

  const int nk = K >> 5;
  for (int kt = 0; kt < nk; ++kt) {
    const int k0 = kt << 5;
    *reinterpret_cast<bf16x8*>(&As[rA][cA])      = *reinterpret_cast<const bf16x8*>(Ag0 + k0);
    *reinterpret_cast<bf16x8*>(&As[rA + 64][cA]) = *reinterpret_cast<const bf16x8*>(Ag1 + k0);
    *reinterpret_cast<bf16x8*>(&Bs[rA][cA])      = *reinterpret_cast<const bf16x8*>(Bg0 + k0);
    *reinterpret_cast<bf16x8*>(&Bs[rA + 64][cA]) = *reinterpret_cast<const bf16x8*>(Bg1 + k0);
    __syncthreads();
    bf16x8 af[4], bfr[4];
    #pragma unroll
    for (int i = 0; i < 4; ++i) {
      af[i]  = *reinterpret_cast<const bf16x8*>(&As[wm + i * 16 + l15][l4 * 8]);
      bfr[i] = *reinterpret_cast<const bf16x8*>(&Bs[wn + i * 16 + l15][l4 * 8]);
    }
    #pragma unroll
    for (int i = 0; i < 4; ++i)
      #pragma unroll
      for (int j = 0; j < 4; ++j)
        acc[i][j] = __builtin_amdgcn_mfma_f32_16x16x32_bf16(af[i], bfr[j], acc[i][j], 0, 0, 0);
    __syncthreads();
  }

  // epilogue: C/D layout col=lane&15, row=(lane>>4)*4+r (m89-verified)
  #pragma unroll
  for (int i = 0; i < 4; ++i) {
    #pragma unroll
    for (int j = 0; j < 4; ++j) {
      const int col = n0 + wn + j * 16 + l15;
      const float bv = bias[col];
      const int rowb = m0 + wm + i * 16 + l4 * 4;
      #pragma unroll
      for (int r = 0; r < 4; ++r) {
        float v = acc[i][j][r] + bv;
        if (OUT_F32)
          reinterpret_cast<float*>(Cout)[(size_t)(rowb + r) * N + col] = v;
        else
          reinterpret_cast<u16*>(Cout)[(size_t)(rowb + r) * N + col] = bf16_bits(v);
      }
    }
  }
}

// ---------------- RoPE + scatter to (H, S, 96) padded, q pre-scaled by 1/sqrt(D) -------
__global__ __launch_bounds__(256) void rope_scatter(const u16* __restrict__ qkv,
                                                    const float* __restrict__ cosb,
                                                    const float* __restrict__ sinb,
                                                    u16* __restrict__ qp,
                                                    u16* __restrict__ kp) {
  const int t = threadIdx.x;
  const int sl = t >> 6;        // 4 s-rows per block
  const int p = t & 63;         // pair id (0..39 active)
  const int s = blockIdx.x * 4 + sl;
  const int h = blockIdx.y;
  const size_t ib = (size_t)s * QKV_N + h * HD;
  const size_t ob = ((size_t)h * S_LEN + s) * HDP;
  if (p < 40) {
    const float scale = 0.1118033988749895f;  // 1/sqrt(80)
    float q1 = bf16_to_f(qkv[ib + p]);
    float q2 = bf16_to_f(qkv[ib + 40 + p]);
    float k1 = bf16_to_f(qkv[ib + E_DIM + p]);
    float k2 = bf16_to_f(qkv[ib + E_DIM + 40 + p]);
    float c1 = cosb[(size_t)s * HD + p],      s1 = sinb[(size_t)s * HD + p];
    float c2 = cosb[(size_t)s * HD + 40 + p], s2 = sinb[(size_t)s * HD + 40 + p];
    // out[:40] = x1*c - x2*s ; out[40:] = x2*c + x1*s
    qp[ob + p]      = bf16_bits((q1 * c1 - q2 * s1) * scale);
    qp[ob + 40 + p] = bf16_bits((q2 * c2 + q1 * s2) * scale);
    kp[ob + p]      = bf16_bits(k1 * c1 - k2 * s1);
    kp[ob + 40 + p] = bf16_bits(k2 * c2 + k1 * s2);
  } else if (p < 48) {
    const int pd = HD + (p - 40) * 2;   // zero-fill pad cols 80..95
    qp[ob + pd] = 0; qp[ob + pd + 1] = 0;
    kp[ob + pd] = 0; kp[ob + pd + 1] = 0;
  }
}

// ---------------- V transpose to (H, 80, S) ----------------
__global__ __launch_bounds__(256) void v_transpose(const u16* __restrict__ qkv,
                                                   u16* __restrict__ vt) {
  const int idx = blockIdx.x * 256 + threadIdx.x;
  const int d = idx % HD;
  const int h = (idx / HD) % NH;
  const int sb = idx / (HD * NH);
  const int s0 = sb * 8;
  if (s0 >= S_LEN) return;
  u16 b[8];
  #pragma unroll
  for (int j = 0; j < 8; ++j)
    b[j] = qkv[(size_t)(s0 + j) * QKV_N + 2 * E_DIM + h * HD + d];
  uint4 pk;
  pk.x = b[0] | ((unsigned)b[1] << 16);
  pk.y = b[2] | ((unsigned)b[3] << 16);
  pk.z = b[4] | ((unsigned)b[5] << 16);
  pk.w = b[6] | ((unsigned)b[7] << 16);
  *reinterpret_cast<uint4*>(&vt[((size_t)h * HD + d) * S_LEN + s0]) = pk;
}

// ---------------- segment-local flash attention ----------------
// grid (S/64, H); 4 waves; wave owns 16 q rows. Q pre-scaled. K-tiles of 64 within segment.
__global__ __launch_bounds__(256) void attn_fwd(const u16* __restrict__ qp,
                                                const u16* __restrict__ kp,
                                                const u16* __restrict__ vt,
                                                const int* __restrict__ cu, int ncu,
                                                u16* __restrict__ ao) {
  __shared__ u16 Pl[4][16][72];  // per-wave P tile 16x64, +8 pad
  const int h = blockIdx.y;
  const int q0 = blockIdx.x * 64;
  const int wave = threadIdx.x >> 6;
  const int lane = threadIdx.x & 63;
  const int l15 = lane & 15, l4 = lane >> 4;
  const int qr = q0 + wave * 16;

  int lo = 0, hi = S_LEN;
  for (int i = 0; i + 1 < ncu; ++i) {
    int a = cu[i], b = cu[i + 1];
    if (q0 >= a && q0 < b) { lo = a; hi = b; }
  }

  const u16* qh = qp + (size_t)h * S_LEN * HDP;
  const u16* kh = kp + (size_t)h * S_LEN * HDP;
  const u16* vh = vt + (size_t)h * HD * S_LEN;

  bf16x8 qf[3];
  #pragma unroll
  for (int c = 0; c < 3; ++c)
    qf[c] = *reinterpret_cast<const bf16x8*>(&qh[(size_t)(qr + l15) * HDP + c * 32 + l4 * 8]);

  f32x4 oacc[5] = {};
  float mrow[4], lrow[4];
  #pragma unroll
  for (int r = 0; r < 4; ++r) { mrow[r] = -INFINITY; lrow[r] = 0.f; }
  const float L2E = 1.4426950408889634f;

  for (int kb = lo; kb < hi; kb += 64) {
    // QK^T: A=Q frag (rows=lane&15), B=K^T frag (cols=lane&15 are k-indices)
    f32x4 sc[4];
    #pragma unroll
    for (int f = 0; f < 4; ++f) {
      f32x4 z = {0.f, 0.f, 0.f, 0.f};
      sc[f] = z;
      #pragma unroll
      for (int c = 0; c < 3; ++c) {
        bf16x8 kf = *reinterpret_cast<const bf16x8*>(
            &kh[(size_t)(kb + f * 16 + l15) * HDP + c * 32 + l4 * 8]);
        sc[f] = __builtin_amdgcn_mfma_f32_16x16x32_bf16(qf[c], kf, sc[f], 0, 0, 0);
      }
    }
    // mask + row max (rows live on (lane>>4)*4+r, cols on lane&15)
    float scv[4][4], tm[4];
    #pragma unroll
    for (int r = 0; r < 4; ++r) tm[r] = -INFINITY;
    #pragma unroll
    for (int f = 0; f < 4; ++f) {
      const bool valid = (kb + f * 16 + l15) < hi;
      #pragma unroll
      for (int r = 0; r < 4; ++r) {
        float v = valid ? sc[f][r] : -INFINITY;
        scv[f][r] = v;
        tm[r] = fmaxf(tm[r], v);
      }
    }
    #pragma unroll
    for (int off = 1; off < 16; off <<= 1)
      #pragma unroll
      for (int r = 0; r < 4; ++r)
        tm[r] = fmaxf(tm[r], __shfl_xor(tm[r], off, 64));
    float corr[4], rs[4];
    #pragma unroll
    for (int r = 0; r < 4; ++r) {
      float mn = fmaxf(mrow[r], tm[r]);
      corr[r] = exp2f((mrow[r] - mn) * L2E);
      mrow[r] = mn;
      rs[r] = 0.f;
    }
    // P = exp(S - m), bf16 into LDS (layout flip C->A), row sums
    #pragma unroll
    for (int f = 0; f < 4; ++f)
      #pragma unroll
      for (int r = 0; r < 4; ++r) {
        float p = exp2f((scv[f][r] - mrow[r]) * L2E);
        rs[r] += p;
        Pl[wave][l4 * 4 + r][f * 16 + l15] = bf16_bits(p);
      }
    #pragma unroll
    for (int off = 1; off < 16; off <<= 1)
      #pragma unroll
      for (int r = 0; r < 4; ++r)
        rs[r] += __shfl_xor(rs[r], off, 64);
    #pragma unroll
    for (int r = 0; r < 4; ++r)
      lrow[r] = lrow[r] * corr[r] + rs[r];
    #pragma unroll
    for (int df = 0; df < 5; ++df)
      #pragma unroll
      for (int r = 0; r < 4; ++r)
        oacc[df][r] *= corr[r];
    asm volatile("s_waitcnt lgkmcnt(0)" ::: "memory");  // own-wave P writes visible
    // PV: A=P (rows=lane&15 from LDS), B=V^T (cols=lane&15 are d, k contig from vt)
    #pragma unroll
    for (int kc = 0; kc < 2; ++kc) {
      bf16x8 pf = *reinterpret_cast<const bf16x8*>(&Pl[wave][l15][kc * 32 + l4 * 8]);
      #pragma unroll
      for (int df = 0; df < 5; ++df) {
        bf16x8 vf = *reinterpret_cast<const bf16x8*>(
            &vh[(size_t)(df * 16 + l15) * S_LEN + kb + kc * 32 + l4 * 8]);
        oacc[df] = __builtin_amdgcn_mfma_f32_16x16x32_bf16(pf, vf, oacc[df], 0, 0, 0);
      }
    }
  }
  #pragma unroll
  for (int df = 0; df < 5; ++df)
    #pragma unroll
    for (int r = 0; r < 4; ++r) {
      float v = oacc[df][r] / lrow[r];
      ao[(size_t)(qr + l4 * 4 + r) * E_DIM + h * HD + df * 16 + l15] = bf16_bits(v);
    }
}

// ---------------- host launch ----------------
extern "C" void kernel_launch(void* const* d_in, const int* in_sizes, int n_in,
                              void* d_out, int out_size, void* d_ws, size_t ws_size,
                              hipStream_t stream) {
  const float* x      = (const float*)d_in[0];
  const int*   cu     = (const int*)d_in[1];
  const float* cosb   = (const float*)d_in[2];
  const float* sinb   = (const float*)d_in[3];
  const float* qkv_w  = (const float*)d_in[4];
  const float* qkv_b  = (const float*)d_in[5];
  const float* proj_w = (const float*)d_in[6];
  const float* proj_b = (const float*)d_in[7];
  float* out = (float*)d_out;

  u16* xb     = (u16*)d_ws;
  u16* wqkvb  = xb     + (size_t)S_LEN * E_DIM;          // 3,932,160
  u16* wprojb = wqkvb  + (size_t)3 * E_DIM * E_DIM;      // +4,915,200
  u16* qkv    = wprojb + (size_t)E_DIM * E_DIM;          // +1,638,400
  u16* qp     = qkv    + (size_t)S_LEN * QKV_N;          // +11,796,480
  u16* kp     = qp     + (size_t)NH * S_LEN * HDP;       // +4,718,592
  u16* vt     = kp     + (size_t)NH * S_LEN * HDP;       // +4,718,592
  u16* attn   = vt     + (size_t)NH * HD * S_LEN;        // +3,932,160  (total ~75.5 MiB)

  int n4;
  n4 = S_LEN * E_DIM / 4;
  f32_to_bf16_k<<<(n4 + 255) / 256, 256, 0, stream>>>(x, xb, n4);
  n4 = 3 * E_DIM * E_DIM / 4;
  f32_to_bf16_k<<<(n4 + 255) / 256, 256, 0, stream>>>(qkv_w, wqkvb, n4);
  n4 = E_DIM * E_DIM / 4;
  f32_to_bf16_k<<<(n4 + 255) / 256, 256, 0, stream>>>(proj_w, wprojb, n4);

  gemm_nt<0><<<dim3(QKV_N / 128, S_LEN / 128), 256, 0, stream>>>(
      xb, wqkvb, qkv_b, qkv, S_LEN, QKV_N, E_DIM);

  rope_scatter<<<dim3(S_LEN / 4, NH), 256, 0, stream>>>(qkv, cosb, sinb, qp, kp);
  v_transpose<<<(NH * HD * (S_LEN / 8)) / 256, 256, 0, stream>>>(qkv, vt);

  attn_fwd<<<dim3(S_LEN / 64, NH), 256, 0, stream>>>(qp, kp, vt, cu, in_sizes[1], attn);

  gemm_nt<1><<<dim3(E_DIM / 128, S_LEN / 128), 256, 0, stream>>>(
      attn, wprojb, proj_b, out, S_LEN, E_DIM, E_DIM);
}

// Round 2
// 145.897 us; speedup vs baseline: 1.1841x; 1.1841x over previous
//
#include <hip/hip_runtime.h>
#include <hip/hip_bf16.h>

#define S_LEN 3072
#define E_DIM 1280
#define NH 16
#define HD 80      // head dim
#define HDP 96     // head dim padded to 3*32 for K=32 MFMA chunks
#define QKV_N 3840

typedef unsigned short u16;
typedef __bf16 bf16x8 __attribute__((ext_vector_type(8)));
typedef float f32x4 __attribute__((ext_vector_type(4)));

__device__ __forceinline__ u16 bf16_bits(float f) {
  __hip_bfloat16 b = __float2bfloat16(f);
  return *reinterpret_cast<u16*>(&b);
}
__device__ __forceinline__ float bf16_to_f(u16 u) {
  unsigned int x = ((unsigned int)u) << 16;
  return __uint_as_float(x);
}
__device__ __forceinline__ void gload_lds16(const u16* g, u16* l) {
  __builtin_amdgcn_global_load_lds(
      (const __attribute__((address_space(1))) void*)g,
      (__attribute__((address_space(3))) void*)l, 16, 0, 0);
}
__device__ __forceinline__ int imin(int a, int b) { return a < b ? a : b; }

// ---------------- fp32 -> bf16 convert (vectorized) ----------------
__global__ __launch_bounds__(256) void f32_to_bf16_k(const float* __restrict__ src,
                                                     u16* __restrict__ dst, int n4) {
  int i = blockIdx.x * 256 + threadIdx.x;
  if (i >= n4) return;
  float4 v = reinterpret_cast<const float4*>(src)[i];
  ushort4 o;
  o.x = bf16_bits(v.x); o.y = bf16_bits(v.y); o.z = bf16_bits(v.z); o.w = bf16_bits(v.w);
  reinterpret_cast<ushort4*>(dst)[i] = o;
}

// ---------------- NT GEMM (m97 structure): C[M][N] = A[M][K] * B[N][K]^T + bias ----
// global_load_lds width-16 staging into linear [128][32] LDS, 2 barriers/K-step.
template<int OUT_F32>
__global__ __launch_bounds__(256) void gemm_nt(const u16* __restrict__ A,
                                               const u16* __restrict__ B,
                                               const float* __restrict__ bias,
                                               void* __restrict__ Cout,
                                               int M, int N, int K, int nbx) {
  __shared__ u16 As[128 * 32];
  __shared__ u16 Bs[128 * 32];
  const int t = threadIdx.x;
  const int lane = t & 63;
  const int wave = t >> 6;
  const int l15 = lane & 15, l4 = lane >> 4;
  const int wm = (wave >> 1) * 64, wn = (wave & 1) * 64;

  // bijective XCD swizzle (gridDim.x % 8 == 0 for both call sites)
  const int nwg = gridDim.x;
  const int lg = (blockIdx.x & 7) * (nwg >> 3) + (blockIdx.x >> 3);
  const int m0 = (lg / nbx) * 128, n0 = (lg % nbx) * 128;

  // staging: 512 chunks of 16B per tile; thread t covers chunks t and t+256
  const int c0 = t, c1 = t + 256;
  const int r0 = c0 >> 2, cc0 = (c0 & 3) << 3;
  const int r1 = c1 >> 2, cc1 = (c1 & 3) << 3;
  const u16* gA0 = A + (size_t)(m0 + r0) * K + cc0;
  const u16* gA1 = A + (size_t)(m0 + r1) * K + cc1;
  const u16* gB0 = B + (size_t)(n0 + r0) * K + cc0;
  const u16* gB1 = B + (size_t)(n0 + r1) * K + cc1;
  u16* lA0 = &As[c0 * 8];
  u16* lA1 = &As[c1 * 8];
  u16* lB0 = &Bs[c0 * 8];
  u16* lB1 = &Bs[c1 * 8];

  f32x4 acc[4][4] = {};

  const int nk = K >> 5;
  for (int kt = 0; kt < nk; ++kt) {
    const int k0 = kt << 5;
    gload_lds16(gA0 + k0, lA0);
    gload_lds16(gA1 + k0, lA1);
    gload_lds16(gB0 + k0, lB0);
    gload_lds16(gB1 + k0, lB1);
    __syncthreads();   // drains vmcnt -> LDS tile complete
    bf16x8 af[4], bfr[4];
    #pragma unroll
    for (int i = 0; i < 4; ++i) {
      af[i]  = *reinterpret_cast<const bf16x8*>(&As[(wm + i * 16 + l15) * 32 + l4 * 8]);
      bfr[i] = *reinterpret_cast<const bf16x8*>(&Bs[(wn + i * 16 + l15) * 32 + l4 * 8]);
    }
    __builtin_amdgcn_s_setprio(1);
    #pragma unroll
    for (int i = 0; i < 4; ++i)
      #pragma unroll
      for (int j = 0; j < 4; ++j)
        acc[i][j] = __builtin_amdgcn_mfma_f32_16x16x32_bf16(af[i], bfr[j], acc[i][j], 0, 0, 0);
    __builtin_amdgcn_s_setprio(0);
    __syncthreads();
  }

  // epilogue: C/D layout col=lane&15, row=(lane>>4)*4+r
  #pragma unroll
  for (int i = 0; i < 4; ++i) {
    #pragma unroll
    for (int j = 0; j < 4; ++j) {
      const int col = n0 + wn + j * 16 + l15;
      const float bv = bias[col];
      const int rowb = m0 + wm + i * 16 + l4 * 4;
      #pragma unroll
      for (int r = 0; r < 4; ++r) {
        float v = acc[i][j][r] + bv;
        if (OUT_F32)
          reinterpret_cast<float*>(Cout)[(size_t)(rowb + r) * N + col] = v;
        else
          reinterpret_cast<u16*>(Cout)[(size_t)(rowb + r) * N + col] = bf16_bits(v);
      }
    }
  }
}

// ---------------- RoPE + scatter to (H, S, 96) padded, q pre-scaled by 1/sqrt(D) -------
__global__ __launch_bounds__(256) void rope_scatter(const u16* __restrict__ qkv,
                                                    const float* __restrict__ cosb,
                                                    const float* __restrict__ sinb,
                                                    u16* __restrict__ qp,
                                                    u16* __restrict__ kp) {
  const int t = threadIdx.x;
  const int sl = t >> 6;        // 4 s-rows per block
  const int p = t & 63;         // pair id (0..39 active)
  const int s = blockIdx.x * 4 + sl;
  const int h = blockIdx.y;
  const size_t ib = (size_t)s * QKV_N + h * HD;
  const size_t ob = ((size_t)h * S_LEN + s) * HDP;
  if (p < 40) {
    const float scale = 0.1118033988749895f;  // 1/sqrt(80)
    float q1 = bf16_to_f(qkv[ib + p]);
    float q2 = bf16_to_f(qkv[ib + 40 + p]);
    float k1 = bf16_to_f(qkv[ib + E_DIM + p]);
    float k2 = bf16_to_f(qkv[ib + E_DIM + 40 + p]);
    float c1 = cosb[(size_t)s * HD + p],      s1 = sinb[(size_t)s * HD + p];
    float c2 = cosb[(size_t)s * HD + 40 + p], s2 = sinb[(size_t)s * HD + 40 + p];
    qp[ob + p]      = bf16_bits((q1 * c1 - q2 * s1) * scale);
    qp[ob + 40 + p] = bf16_bits((q2 * c2 + q1 * s2) * scale);
    kp[ob + p]      = bf16_bits(k1 * c1 - k2 * s1);
    kp[ob + 40 + p] = bf16_bits(k2 * c2 + k1 * s2);
  } else if (p < 48) {
    const int pd = HD + (p - 40) * 2;   // zero-fill pad cols 80..95
    qp[ob + pd] = 0; qp[ob + pd + 1] = 0;
    kp[ob + pd] = 0; kp[ob + pd + 1] = 0;
  }
}

// ---------------- V transpose to (H, 80, S) ----------------
__global__ __launch_bounds__(256) void v_transpose(const u16* __restrict__ qkv,
                                                   u16* __restrict__ vt) {
  const int idx = blockIdx.x * 256 + threadIdx.x;
  const int d = idx % HD;
  const int h = (idx / HD) % NH;
  const int sb = idx / (HD * NH);
  const int s0 = sb * 8;
  if (s0 >= S_LEN) return;
  u16 b[8];
  #pragma unroll
  for (int j = 0; j < 8; ++j)
    b[j] = qkv[(size_t)(s0 + j) * QKV_N + 2 * E_DIM + h * HD + d];
  uint4 pk;
  pk.x = b[0] | ((unsigned)b[1] << 16);
  pk.y = b[2] | ((unsigned)b[3] << 16);
  pk.z = b[4] | ((unsigned)b[5] << 16);
  pk.w = b[6] | ((unsigned)b[7] << 16);
  *reinterpret_cast<uint4*>(&vt[((size_t)h * HD + d) * S_LEN + s0]) = pk;
}

// ---------------- segment-local flash attention, LDS-staged K, pipelined ----------
// 1D grid of 768 = 16 heads x 48 q-blocks (64 rows). 4 waves; wave owns 16 q rows.
__global__ __launch_bounds__(256) void attn_fwd(const u16* __restrict__ qp,
                                                const u16* __restrict__ kp,
                                                const u16* __restrict__ vt,
                                                const int* __restrict__ cu, int ncu,
                                                u16* __restrict__ ao) {
  __shared__ u16 Ks[2][64][104];  // 64x96 K tile, +8 u16 pad -> 2-way banks (free)
  __shared__ u16 Pl[4][16][72];   // per-wave P tile, +8 pad

  // XCD swizzle: each XCD owns 2 consecutive heads (K+V ~2.1MB fits 4MB L2)
  const int lg = ((blockIdx.x & 7) * 96) + (blockIdx.x >> 3);  // 768 blocks
  const int h = lg / 48;
  const int q0 = (lg % 48) * 64;

  const int t = threadIdx.x;
  const int wave = t >> 6;
  const int lane = t & 63;
  const int l15 = lane & 15, l4 = lane >> 4;
  const int qr = q0 + wave * 16;

  int lo = 0, hi = S_LEN;
  for (int i = 0; i + 1 < ncu; ++i) {
    int a = cu[i], b = cu[i + 1];
    if (q0 >= a && q0 < b) { lo = a; hi = b; }
  }
  const int nt = (hi - lo + 63) >> 6;

  const u16* qh = qp + (size_t)h * S_LEN * HDP;
  const u16* kh = kp + (size_t)h * S_LEN * HDP;
  const u16* vh = vt + (size_t)h * HD * S_LEN;

  bf16x8 qf[3];
  #pragma unroll
  for (int c = 0; c < 3; ++c)
    qf[c] = *reinterpret_cast<const bf16x8*>(&qh[(size_t)(qr + l15) * HDP + c * 32 + l4 * 8]);

  // K-stage mapping: 768 chunks of 16B; thread covers c2 = i*256+t, r=c2/12, cc=c2%12
  const int sr0 = t / 12 * 0;  // (computed per-i below)

  // prologue: stage tile 0 into Ks[0]
  {
    bf16x8 kreg[3];
    #pragma unroll
    for (int i = 0; i < 3; ++i) {
      const int c2 = i * 256 + t;
      const int r = c2 / 12, cc = c2 % 12;
      const int row = imin(lo + r, S_LEN - 1);
      kreg[i] = *reinterpret_cast<const bf16x8*>(&kh[(size_t)row * HDP + cc * 8]);
    }
    #pragma unroll
    for (int i = 0; i < 3; ++i) {
      const int c2 = i * 256 + t;
      const int r = c2 / 12, cc = c2 % 12;
      *reinterpret_cast<bf16x8*>(&Ks[0][r][cc * 8]) = kreg[i];
    }
    __syncthreads();
  }

  f32x4 oacc[5] = {};
  float mrow[4], lrow[4];
  #pragma unroll
  for (int r = 0; r < 4; ++r) { mrow[r] = -INFINITY; lrow[r] = 0.f; }
  const float L2E = 1.4426950408889634f;

  int cur = 0;
  for (int ti = 0; ti < nt; ++ti) {
    const int kb = lo + ti * 64;
    const int kbL = imin(kb, S_LEN - 64);

    // issue V loads for THIS tile early (latency hides under QK + softmax)
    bf16x8 vreg[2][5];
    #pragma unroll
    for (int kc = 0; kc < 2; ++kc)
      #pragma unroll
      for (int df = 0; df < 5; ++df)
        vreg[kc][df] = *reinterpret_cast<const bf16x8*>(
            &vh[(size_t)(df * 16 + l15) * S_LEN + kbL + kc * 32 + l4 * 8]);

    // issue K-stage loads for NEXT tile (written to LDS after compute)
    const bool more = (ti + 1) < nt;
    bf16x8 kreg[3];
    if (more) {
      const int kb2 = lo + (ti + 1) * 64;
      #pragma unroll
      for (int i = 0; i < 3; ++i) {
        const int c2 = i * 256 + t;
        const int r = c2 / 12, cc = c2 % 12;
        const int row = imin(kb2 + r, S_LEN - 1);
        kreg[i] = *reinterpret_cast<const bf16x8*>(&kh[(size_t)row * HDP + cc * 8]);
      }
    }

    // QK^T from LDS
    f32x4 sc[4];
    #pragma unroll
    for (int f = 0; f < 4; ++f) {
      f32x4 z = {0.f, 0.f, 0.f, 0.f};
      sc[f] = z;
    }
    __builtin_amdgcn_s_setprio(1);
    #pragma unroll
    for (int f = 0; f < 4; ++f)
      #pragma unroll
      for (int c = 0; c < 3; ++c) {
        bf16x8 kf = *reinterpret_cast<const bf16x8*>(&Ks[cur][f * 16 + l15][c * 32 + l4 * 8]);
        sc[f] = __builtin_amdgcn_mfma_f32_16x16x32_bf16(qf[c], kf, sc[f], 0, 0, 0);
      }
    __builtin_amdgcn_s_setprio(0);

    // mask + row max (rows on (lane>>4)*4+r, cols on lane&15)
    float scv[4][4], tm[4];
    #pragma unroll
    for (int r = 0; r < 4; ++r) tm[r] = -INFINITY;
    #pragma unroll
    for (int f = 0; f < 4; ++f) {
      const bool valid = (kb + f * 16 + l15) < hi;
      #pragma unroll
      for (int r = 0; r < 4; ++r) {
        float v = valid ? sc[f][r] : -INFINITY;
        scv[f][r] = v;
        tm[r] = fmaxf(tm[r], v);
      }
    }
    #pragma unroll
    for (int off = 1; off < 16; off <<= 1)
      #pragma unroll
      for (int r = 0; r < 4; ++r)
        tm[r] = fmaxf(tm[r], __shfl_xor(tm[r], off, 64));
    float corr[4], rs[4];
    #pragma unroll
    for (int r = 0; r < 4; ++r) {
      float mn = fmaxf(mrow[r], tm[r]);
      corr[r] = exp2f((mrow[r] - mn) * L2E);
      mrow[r] = mn;
      rs[r] = 0.f;
    }
    #pragma unroll
    for (int f = 0; f < 4; ++f)
      #pragma unroll
      for (int r = 0; r < 4; ++r) {
        float p = exp2f((scv[f][r] - mrow[r]) * L2E);
        rs[r] += p;
        Pl[wave][l4 * 4 + r][f * 16 + l15] = bf16_bits(p);
      }
    #pragma unroll
    for (int off = 1; off < 16; off <<= 1)
      #pragma unroll
      for (int r = 0; r < 4; ++r)
        rs[r] += __shfl_xor(rs[r], off, 64);
    #pragma unroll
    for (int r = 0; r < 4; ++r)
      lrow[r] = lrow[r] * corr[r] + rs[r];
    #pragma unroll
    for (int df = 0; df < 5; ++df)
      #pragma unroll
      for (int r = 0; r < 4; ++r)
        oacc[df][r] *= corr[r];
    asm volatile("s_waitcnt lgkmcnt(0)" ::: "memory");  // own-wave P writes visible

    // PV: A=P from LDS, B=V^T from prefetched regs
    __builtin_amdgcn_s_setprio(1);
    #pragma unroll
    for (int kc = 0; kc < 2; ++kc) {
      bf16x8 pf = *reinterpret_cast<const bf16x8*>(&Pl[wave][l15][kc * 32 + l4 * 8]);
      #pragma unroll
      for (int df = 0; df < 5; ++df)
        oacc[df] = __builtin_amdgcn_mfma_f32_16x16x32_bf16(pf, vreg[kc][df], oacc[df], 0, 0, 0);
    }
    __builtin_amdgcn_s_setprio(0);

    // write next K tile into the other buffer (its last readers finished
    // before the PREVIOUS barrier), then one barrier per tile
    if (more) {
      #pragma unroll
      for (int i = 0; i < 3; ++i) {
        const int c2 = i * 256 + t;
        const int r = c2 / 12, cc = c2 % 12;
        *reinterpret_cast<bf16x8*>(&Ks[cur ^ 1][r][cc * 8]) = kreg[i];
      }
    }
    __syncthreads();
    cur ^= 1;
  }

  #pragma unroll
  for (int df = 0; df < 5; ++df)
    #pragma unroll
    for (int r = 0; r < 4; ++r) {
      float v = oacc[df][r] / lrow[r];
      ao[(size_t)(qr + l4 * 4 + r) * E_DIM + h * HD + df * 16 + l15] = bf16_bits(v);
    }
}

// ---------------- host launch ----------------
extern "C" void kernel_launch(void* const* d_in, const int* in_sizes, int n_in,
                              void* d_out, int out_size, void* d_ws, size_t ws_size,
                              hipStream_t stream) {
  const float* x      = (const float*)d_in[0];
  const int*   cu     = (const int*)d_in[1];
  const float* cosb   = (const float*)d_in[2];
  const float* sinb   = (const float*)d_in[3];
  const float* qkv_w  = (const float*)d_in[4];
  const float* qkv_b  = (const float*)d_in[5];
  const float* proj_w = (const float*)d_in[6];
  const float* proj_b = (const float*)d_in[7];
  float* out = (float*)d_out;

  u16* xb     = (u16*)d_ws;
  u16* wqkvb  = xb     + (size_t)S_LEN * E_DIM;
  u16* wprojb = wqkvb  + (size_t)3 * E_DIM * E_DIM;
  u16* qkv    = wprojb + (size_t)E_DIM * E_DIM;
  u16* qp     = qkv    + (size_t)S_LEN * QKV_N;
  u16* kp     = qp     + (size_t)NH * S_LEN * HDP;
  u16* vt     = kp     + (size_t)NH * S_LEN * HDP;
  u16* attn   = vt     + (size_t)NH * HD * S_LEN;

  int n4;
  n4 = S_LEN * E_DIM / 4;
  f32_to_bf16_k<<<(n4 + 255) / 256, 256, 0, stream>>>(x, xb, n4);
  n4 = 3 * E_DIM * E_DIM / 4;
  f32_to_bf16_k<<<(n4 + 255) / 256, 256, 0, stream>>>(qkv_w, wqkvb, n4);
  n4 = E_DIM * E_DIM / 4;
  f32_to_bf16_k<<<(n4 + 255) / 256, 256, 0, stream>>>(proj_w, wprojb, n4);

  gemm_nt<0><<<(QKV_N / 128) * (S_LEN / 128), 256, 0, stream>>>(
      xb, wqkvb, qkv_b, qkv, S_LEN, QKV_N, E_DIM, QKV_N / 128);

  rope_scatter<<<dim3(S_LEN / 4, NH), 256, 0, stream>>>(qkv, cosb, sinb, qp, kp);
  v_transpose<<<(NH * HD * (S_LEN / 8)) / 256, 256, 0, stream>>>(qkv, vt);

  attn_fwd<<<NH * (S_LEN / 64), 256, 0, stream>>>(qp, kp, vt, cu, in_sizes[1], attn);

  gemm_nt<1><<<(E_DIM / 128) * (S_LEN / 128), 256, 0, stream>>>(
      attn, wprojb, proj_b, out, S_LEN, E_DIM, E_DIM, E_DIM / 128);
}

// Round 3
// 127.417 us; speedup vs baseline: 1.3558x; 1.1450x over previous
//
#include <hip/hip_runtime.h>
#include <hip/hip_bf16.h>

#define S_LEN 3072
#define E_DIM 1280
#define NH 16
#define HD 80      // head dim
#define HDP 96     // head dim padded to 3*32 for K=32 MFMA chunks
#define QKV_N 3840

typedef unsigned short u16;
typedef __bf16 bf16x8 __attribute__((ext_vector_type(8)));
typedef float f32x4 __attribute__((ext_vector_type(4)));

__device__ __forceinline__ u16 bf16_bits(float f) {
  __hip_bfloat16 b = __float2bfloat16(f);
  return *reinterpret_cast<u16*>(&b);
}
__device__ __forceinline__ float bf16_to_f(u16 u) {
  unsigned int x = ((unsigned int)u) << 16;
  return __uint_as_float(x);
}
__device__ __forceinline__ void gload_lds16(const u16* g, u16* l) {
  __builtin_amdgcn_global_load_lds(
      (const __attribute__((address_space(1))) void*)g,
      (__attribute__((address_space(3))) void*)l, 16, 0, 0);
}
__device__ __forceinline__ int imin(int a, int b) { return a < b ? a : b; }

// ---------------- fused fp32 -> bf16 convert: x | qkv_w | proj_w ----------------
// dsts are contiguous in ws: xb (983040 f4) | wqkvb (1228800 f4) | wprojb (409600 f4)
#define XB_F4    983040
#define WQKV_F4  1228800
#define WPROJ_F4 409600
__global__ __launch_bounds__(256) void f32_to_bf16_3(const float* __restrict__ sx,
                                                     const float* __restrict__ sq,
                                                     const float* __restrict__ sp,
                                                     u16* __restrict__ dst) {
  int i = blockIdx.x * 256 + threadIdx.x;
  float4 v;
  if (i < XB_F4) v = reinterpret_cast<const float4*>(sx)[i];
  else if (i < XB_F4 + WQKV_F4) v = reinterpret_cast<const float4*>(sq)[i - XB_F4];
  else v = reinterpret_cast<const float4*>(sp)[i - XB_F4 - WQKV_F4];
  ushort4 o;
  o.x = bf16_bits(v.x); o.y = bf16_bits(v.y); o.z = bf16_bits(v.z); o.w = bf16_bits(v.w);
  reinterpret_cast<ushort4*>(dst)[i] = o;
}

// ---------------- NT GEMM: C[M][N] = A[M][K] * B[N][K]^T + bias ----------------
// 128x128 tile, BK=64 (32 MFMA per barrier pair), XOR-swizzled LDS (T2 both-sides):
// physical 16B-chunk = logical chunk ^ (row&7); gload_lds dest stays linear, the
// global SOURCE is pre-swizzled (rule 21); ds_read index XORs with (l15&7).
template<int OUT_F32>
__global__ __launch_bounds__(256) void gemm_nt(const u16* __restrict__ A,
                                               const u16* __restrict__ B,
                                               const float* __restrict__ bias,
                                               void* __restrict__ Cout,
                                               int M, int N, int K, int nbx) {
  __shared__ u16 As[128 * 64];
  __shared__ u16 Bs[128 * 64];
  const int t = threadIdx.x;
  const int lane = t & 63;
  const int wave = t >> 6;
  const int l15 = lane & 15, l4 = lane >> 4;
  const int wm = (wave >> 1) * 64, wn = (wave & 1) * 64;

  // bijective XCD swizzle (gridDim.x % 8 == 0 for both call sites)
  const int nwg = gridDim.x;
  const int lg = (blockIdx.x & 7) * (nwg >> 3) + (blockIdx.x >> 3);
  const int m0 = (lg / nbx) * 128, n0 = (lg % nbx) * 128;

  // staging: 1024 chunks of 16B per operand tile; thread t covers c = i*256+t.
  // physical chunk c -> row = c>>3, logical col-chunk = (c&7) ^ (row&7)
  const u16* gA[4];
  const u16* gB[4];
  u16* lA[4];
  u16* lB[4];
  #pragma unroll
  for (int i = 0; i < 4; ++i) {
    const int c = i * 256 + t;
    const int row = c >> 3;
    const int col = ((c & 7) ^ (row & 7)) * 8;
    gA[i] = A + (size_t)(m0 + row) * K + col;
    gB[i] = B + (size_t)(n0 + row) * K + col;
    lA[i] = &As[c * 8];
    lB[i] = &Bs[c * 8];
  }

  // fragment LDS indexes (kt-invariant): row*64 + ((kk*4+l4)^(l15&7))*8
  int aoff[4][2], boff[4][2];
  #pragma unroll
  for (int i = 0; i < 4; ++i)
    #pragma unroll
    for (int kk = 0; kk < 2; ++kk) {
      aoff[i][kk] = (wm + i * 16 + l15) * 64 + ((kk * 4 + l4) ^ (l15 & 7)) * 8;
      boff[i][kk] = (wn + i * 16 + l15) * 64 + ((kk * 4 + l4) ^ (l15 & 7)) * 8;
    }

  f32x4 acc[4][4] = {};

  const int nk = K >> 6;
  for (int kt = 0; kt < nk; ++kt) {
    const int k0 = kt << 6;
    #pragma unroll
    for (int i = 0; i < 4; ++i) gload_lds16(gA[i] + k0, lA[i]);
    #pragma unroll
    for (int i = 0; i < 4; ++i) gload_lds16(gB[i] + k0, lB[i]);
    __syncthreads();   // drains vmcnt -> LDS tile complete
    bf16x8 af[4][2], bfr[4][2];
    #pragma unroll
    for (int i = 0; i < 4; ++i)
      #pragma unroll
      for (int kk = 0; kk < 2; ++kk) {
        af[i][kk]  = *reinterpret_cast<const bf16x8*>(&As[aoff[i][kk]]);
        bfr[i][kk] = *reinterpret_cast<const bf16x8*>(&Bs[boff[i][kk]]);
      }
    __builtin_amdgcn_s_setprio(1);
    #pragma unroll
    for (int kk = 0; kk < 2; ++kk)
      #pragma unroll
      for (int i = 0; i < 4; ++i)
        #pragma unroll
        for (int j = 0; j < 4; ++j)
          acc[i][j] = __builtin_amdgcn_mfma_f32_16x16x32_bf16(af[i][kk], bfr[j][kk],
                                                              acc[i][j], 0, 0, 0);
    __builtin_amdgcn_s_setprio(0);
    __syncthreads();
  }

  // epilogue: C/D layout col=lane&15, row=(lane>>4)*4+r
  #pragma unroll
  for (int i = 0; i < 4; ++i) {
    #pragma unroll
    for (int j = 0; j < 4; ++j) {
      const int col = n0 + wn + j * 16 + l15;
      const float bv = bias[col];
      const int rowb = m0 + wm + i * 16 + l4 * 4;
      #pragma unroll
      for (int r = 0; r < 4; ++r) {
        float v = acc[i][j][r] + bv;
        if (OUT_F32)
          reinterpret_cast<float*>(Cout)[(size_t)(rowb + r) * N + col] = v;
        else
          reinterpret_cast<u16*>(Cout)[(size_t)(rowb + r) * N + col] = bf16_bits(v);
      }
    }
  }
}

// ---------------- RoPE + scatter to (H, S, 96) padded, q pre-scaled by 1/sqrt(D) -------
__global__ __launch_bounds__(256) void rope_scatter(const u16* __restrict__ qkv,
                                                    const float* __restrict__ cosb,
                                                    const float* __restrict__ sinb,
                                                    u16* __restrict__ qp,
                                                    u16* __restrict__ kp) {
  const int t = threadIdx.x;
  const int sl = t >> 6;        // 4 s-rows per block
  const int p = t & 63;         // pair id (0..39 active)
  const int s = blockIdx.x * 4 + sl;
  const int h = blockIdx.y;
  const size_t ib = (size_t)s * QKV_N + h * HD;
  const size_t ob = ((size_t)h * S_LEN + s) * HDP;
  if (p < 40) {
    const float scale = 0.1118033988749895f;  // 1/sqrt(80)
    float q1 = bf16_to_f(qkv[ib + p]);
    float q2 = bf16_to_f(qkv[ib + 40 + p]);
    float k1 = bf16_to_f(qkv[ib + E_DIM + p]);
    float k2 = bf16_to_f(qkv[ib + E_DIM + 40 + p]);
    float c1 = cosb[(size_t)s * HD + p],      s1 = sinb[(size_t)s * HD + p];
    float c2 = cosb[(size_t)s * HD + 40 + p], s2 = sinb[(size_t)s * HD + 40 + p];
    qp[ob + p]      = bf16_bits((q1 * c1 - q2 * s1) * scale);
    qp[ob + 40 + p] = bf16_bits((q2 * c2 + q1 * s2) * scale);
    kp[ob + p]      = bf16_bits(k1 * c1 - k2 * s1);
    kp[ob + 40 + p] = bf16_bits(k2 * c2 + k1 * s2);
  } else if (p < 48) {
    const int pd = HD + (p - 40) * 2;   // zero-fill pad cols 80..95
    qp[ob + pd] = 0; qp[ob + pd + 1] = 0;
    kp[ob + pd] = 0; kp[ob + pd + 1] = 0;
  }
}

// ---------------- V transpose to (H, 80, S) ----------------
__global__ __launch_bounds__(256) void v_transpose(const u16* __restrict__ qkv,
                                                   u16* __restrict__ vt) {
  const int idx = blockIdx.x * 256 + threadIdx.x;
  const int d = idx % HD;
  const int h = (idx / HD) % NH;
  const int sb = idx / (HD * NH);
  const int s0 = sb * 8;
  if (s0 >= S_LEN) return;
  u16 b[8];
  #pragma unroll
  for (int j = 0; j < 8; ++j)
    b[j] = qkv[(size_t)(s0 + j) * QKV_N + 2 * E_DIM + h * HD + d];
  uint4 pk;
  pk.x = b[0] | ((unsigned)b[1] << 16);
  pk.y = b[2] | ((unsigned)b[3] << 16);
  pk.z = b[4] | ((unsigned)b[5] << 16);
  pk.w = b[6] | ((unsigned)b[7] << 16);
  *reinterpret_cast<uint4*>(&vt[((size_t)h * HD + d) * S_LEN + s0]) = pk;
}

// ---------------- segment-local flash attention, LDS-staged K, pipelined ----------
// 1D grid of 768 = 16 heads x 48 q-blocks (64 rows). 4 waves; wave owns 16 q rows.
__global__ __launch_bounds__(256) void attn_fwd(const u16* __restrict__ qp,
                                                const u16* __restrict__ kp,
                                                const u16* __restrict__ vt,
                                                const int* __restrict__ cu, int ncu,
                                                u16* __restrict__ ao) {
  __shared__ u16 Ks[2][64][104];  // 64x96 K tile, +8 u16 pad -> 2-way banks (free)
  __shared__ u16 Pl[4][16][72];   // per-wave P tile, +8 pad

  // XCD swizzle: each XCD owns 2 consecutive heads (K+V ~2.1MB fits 4MB L2)
  const int lg = ((blockIdx.x & 7) * 96) + (blockIdx.x >> 3);  // 768 blocks
  const int h = lg / 48;
  const int q0 = (lg % 48) * 64;

  const int t = threadIdx.x;
  const int wave = t >> 6;
  const int lane = t & 63;
  const int l15 = lane & 15, l4 = lane >> 4;
  const int qr = q0 + wave * 16;

  int lo = 0, hi = S_LEN;
  for (int i = 0; i + 1 < ncu; ++i) {
    int a = cu[i], b = cu[i + 1];
    if (q0 >= a && q0 < b) { lo = a; hi = b; }
  }
  const int nt = (hi - lo + 63) >> 6;

  const u16* qh = qp + (size_t)h * S_LEN * HDP;
  const u16* kh = kp + (size_t)h * S_LEN * HDP;
  const u16* vh = vt + (size_t)h * HD * S_LEN;

  bf16x8 qf[3];
  #pragma unroll
  for (int c = 0; c < 3; ++c)
    qf[c] = *reinterpret_cast<const bf16x8*>(&qh[(size_t)(qr + l15) * HDP + c * 32 + l4 * 8]);

  // prologue: stage tile 0 into Ks[0]
  {
    bf16x8 kreg[3];
    #pragma unroll
    for (int i = 0; i < 3; ++i) {
      const int c2 = i * 256 + t;
      const int r = c2 / 12, cc = c2 % 12;
      const int row = imin(lo + r, S_LEN - 1);
      kreg[i] = *reinterpret_cast<const bf16x8*>(&kh[(size_t)row * HDP + cc * 8]);
    }
    #pragma unroll
    for (int i = 0; i < 3; ++i) {
      const int c2 = i * 256 + t;
      const int r = c2 / 12, cc = c2 % 12;
      *reinterpret_cast<bf16x8*>(&Ks[0][r][cc * 8]) = kreg[i];
    }
    __syncthreads();
  }

  f32x4 oacc[5] = {};
  float mrow[4], lrow[4];
  #pragma unroll
  for (int r = 0; r < 4; ++r) { mrow[r] = -INFINITY; lrow[r] = 0.f; }
  const float L2E = 1.4426950408889634f;

  int cur = 0;
  for (int ti = 0; ti < nt; ++ti) {
    const int kb = lo + ti * 64;
    const int kbL = imin(kb, S_LEN - 64);

    // issue V loads for THIS tile early (latency hides under QK + softmax)
    bf16x8 vreg[2][5];
    #pragma unroll
    for (int kc = 0; kc < 2; ++kc)
      #pragma unroll
      for (int df = 0; df < 5; ++df)
        vreg[kc][df] = *reinterpret_cast<const bf16x8*>(
            &vh[(size_t)(df * 16 + l15) * S_LEN + kbL + kc * 32 + l4 * 8]);

    // issue K-stage loads for NEXT tile (written to LDS after compute)
    const bool more = (ti + 1) < nt;
    bf16x8 kreg[3];
    if (more) {
      const int kb2 = lo + (ti + 1) * 64;
      #pragma unroll
      for (int i = 0; i < 3; ++i) {
        const int c2 = i * 256 + t;
        const int r = c2 / 12, cc = c2 % 12;
        const int row = imin(kb2 + r, S_LEN - 1);
        kreg[i] = *reinterpret_cast<const bf16x8*>(&kh[(size_t)row * HDP + cc * 8]);
      }
    }

    // QK^T from LDS
    f32x4 sc[4];
    #pragma unroll
    for (int f = 0; f < 4; ++f) {
      f32x4 z = {0.f, 0.f, 0.f, 0.f};
      sc[f] = z;
    }
    __builtin_amdgcn_s_setprio(1);
    #pragma unroll
    for (int f = 0; f < 4; ++f)
      #pragma unroll
      for (int c = 0; c < 3; ++c) {
        bf16x8 kf = *reinterpret_cast<const bf16x8*>(&Ks[cur][f * 16 + l15][c * 32 + l4 * 8]);
        sc[f] = __builtin_amdgcn_mfma_f32_16x16x32_bf16(qf[c], kf, sc[f], 0, 0, 0);
      }
    __builtin_amdgcn_s_setprio(0);

    // mask + row max (rows on (lane>>4)*4+r, cols on lane&15)
    float scv[4][4], tm[4];
    #pragma unroll
    for (int r = 0; r < 4; ++r) tm[r] = -INFINITY;
    #pragma unroll
    for (int f = 0; f < 4; ++f) {
      const bool valid = (kb + f * 16 + l15) < hi;
      #pragma unroll
      for (int r = 0; r < 4; ++r) {
        float v = valid ? sc[f][r] : -INFINITY;
        scv[f][r] = v;
        tm[r] = fmaxf(tm[r], v);
      }
    }
    #pragma unroll
    for (int off = 1; off < 16; off <<= 1)
      #pragma unroll
      for (int r = 0; r < 4; ++r)
        tm[r] = fmaxf(tm[r], __shfl_xor(tm[r], off, 64));
    float corr[4], rs[4];
    #pragma unroll
    for (int r = 0; r < 4; ++r) {
      float mn = fmaxf(mrow[r], tm[r]);
      corr[r] = exp2f((mrow[r] - mn) * L2E);
      mrow[r] = mn;
      rs[r] = 0.f;
    }
    #pragma unroll
    for (int f = 0; f < 4; ++f)
      #pragma unroll
      for (int r = 0; r < 4; ++r) {
        float p = exp2f((scv[f][r] - mrow[r]) * L2E);
        rs[r] += p;
        Pl[wave][l4 * 4 + r][f * 16 + l15] = bf16_bits(p);
      }
    #pragma unroll
    for (int off = 1; off < 16; off <<= 1)
      #pragma unroll
      for (int r = 0; r < 4; ++r)
        rs[r] += __shfl_xor(rs[r], off, 64);
    #pragma unroll
    for (int r = 0; r < 4; ++r)
      lrow[r] = lrow[r] * corr[r] + rs[r];
    #pragma unroll
    for (int df = 0; df < 5; ++df)
      #pragma unroll
      for (int r = 0; r < 4; ++r)
        oacc[df][r] *= corr[r];
    asm volatile("s_waitcnt lgkmcnt(0)" ::: "memory");  // own-wave P writes visible

    // PV: A=P from LDS, B=V^T from prefetched regs
    __builtin_amdgcn_s_setprio(1);
    #pragma unroll
    for (int kc = 0; kc < 2; ++kc) {
      bf16x8 pf = *reinterpret_cast<const bf16x8*>(&Pl[wave][l15][kc * 32 + l4 * 8]);
      #pragma unroll
      for (int df = 0; df < 5; ++df)
        oacc[df] = __builtin_amdgcn_mfma_f32_16x16x32_bf16(pf, vreg[kc][df], oacc[df], 0, 0, 0);
    }
    __builtin_amdgcn_s_setprio(0);

    // write next K tile into the other buffer, then one barrier per tile
    if (more) {
      #pragma unroll
      for (int i = 0; i < 3; ++i) {
        const int c2 = i * 256 + t;
        const int r = c2 / 12, cc = c2 % 12;
        *reinterpret_cast<bf16x8*>(&Ks[cur ^ 1][r][cc * 8]) = kreg[i];
      }
    }
    __syncthreads();
    cur ^= 1;
  }

  #pragma unroll
  for (int df = 0; df < 5; ++df)
    #pragma unroll
    for (int r = 0; r < 4; ++r) {
      float v = oacc[df][r] / lrow[r];
      ao[(size_t)(qr + l4 * 4 + r) * E_DIM + h * HD + df * 16 + l15] = bf16_bits(v);
    }
}

// ---------------- host launch ----------------
extern "C" void kernel_launch(void* const* d_in, const int* in_sizes, int n_in,
                              void* d_out, int out_size, void* d_ws, size_t ws_size,
                              hipStream_t stream) {
  const float* x      = (const float*)d_in[0];
  const int*   cu     = (const int*)d_in[1];
  const float* cosb   = (const float*)d_in[2];
  const float* sinb   = (const float*)d_in[3];
  const float* qkv_w  = (const float*)d_in[4];
  const float* qkv_b  = (const float*)d_in[5];
  const float* proj_w = (const float*)d_in[6];
  const float* proj_b = (const float*)d_in[7];
  float* out = (float*)d_out;

  u16* xb     = (u16*)d_ws;
  u16* wqkvb  = xb     + (size_t)S_LEN * E_DIM;
  u16* wprojb = wqkvb  + (size_t)3 * E_DIM * E_DIM;
  u16* qkv    = wprojb + (size_t)E_DIM * E_DIM;
  u16* qp     = qkv    + (size_t)S_LEN * QKV_N;
  u16* kp     = qp     + (size_t)NH * S_LEN * HDP;
  u16* vt     = kp     + (size_t)NH * S_LEN * HDP;
  u16* attn   = vt     + (size_t)NH * HD * S_LEN;

  const int nf4 = XB_F4 + WQKV_F4 + WPROJ_F4;   // 2,621,440
  f32_to_bf16_3<<<nf4 / 256, 256, 0, stream>>>(x, qkv_w, proj_w, xb);

  gemm_nt<0><<<(QKV_N / 128) * (S_LEN / 128), 256, 0, stream>>>(
      xb, wqkvb, qkv_b, qkv, S_LEN, QKV_N, E_DIM, QKV_N / 128);

  rope_scatter<<<dim3(S_LEN / 4, NH), 256, 0, stream>>>(qkv, cosb, sinb, qp, kp);
  v_transpose<<<(NH * HD * (S_LEN / 8)) / 256, 256, 0, stream>>>(qkv, vt);

  attn_fwd<<<NH * (S_LEN / 64), 256, 0, stream>>>(qp, kp, vt, cu, in_sizes[1], attn);

  gemm_nt<1><<<(E_DIM / 128) * (S_LEN / 128), 256, 0, stream>>>(
      attn, wprojb, proj_b, out, S_LEN, E_DIM, E_DIM, E_DIM / 128);
}

// Round 4
// 122.191 us; speedup vs baseline: 1.4138x; 1.0428x over previous
//
#include <hip/hip_runtime.h>
#include <hip/hip_bf16.h>

#define S_LEN 3072
#define E_DIM 1280
#define NH 16
#define HD 80      // head dim
#define HDP 96     // head dim padded to 3*32 for K=32 MFMA chunks
#define QKV_N 3840

typedef unsigned short u16;
typedef unsigned int u32;
typedef __bf16 bf16x8 __attribute__((ext_vector_type(8)));
typedef float f32x4 __attribute__((ext_vector_type(4)));

__device__ __forceinline__ u16 bf16_bits(float f) {
  __hip_bfloat16 b = __float2bfloat16(f);
  return *reinterpret_cast<u16*>(&b);
}
__device__ __forceinline__ float bf16_to_f(u16 u) {
  unsigned int x = ((unsigned int)u) << 16;
  return __uint_as_float(x);
}
__device__ __forceinline__ void gload_lds16(const u16* g, u16* l) {
  __builtin_amdgcn_global_load_lds(
      (const __attribute__((address_space(1))) void*)g,
      (__attribute__((address_space(3))) void*)l, 16, 0, 0);
}
__device__ __forceinline__ int imin(int a, int b) { return a < b ? a : b; }

// ---------------- fused fp32 -> bf16 convert: x | qkv_w | proj_w ----------------
#define XB_F4    983040
#define WQKV_F4  1228800
#define WPROJ_F4 409600
__global__ __launch_bounds__(256) void f32_to_bf16_3(const float* __restrict__ sx,
                                                     const float* __restrict__ sq,
                                                     const float* __restrict__ sp,
                                                     u16* __restrict__ dst) {
  int i = blockIdx.x * 256 + threadIdx.x;
  float4 v;
  if (i < XB_F4) v = reinterpret_cast<const float4*>(sx)[i];
  else if (i < XB_F4 + WQKV_F4) v = reinterpret_cast<const float4*>(sq)[i - XB_F4];
  else v = reinterpret_cast<const float4*>(sp)[i - XB_F4 - WQKV_F4];
  ushort4 o;
  o.x = bf16_bits(v.x); o.y = bf16_bits(v.y); o.z = bf16_bits(v.z); o.w = bf16_bits(v.w);
  reinterpret_cast<ushort4*>(dst)[i] = o;
}

// ---------------- NT GEMM: C[M][N] = A[M][K] * B[N][K]^T + bias ----------------
// 128x128 tile, BK=64, XOR-swizzled LDS (T2 both-sides via pre-swizzled source).
template<int OUT_F32>
__global__ __launch_bounds__(256) void gemm_nt(const u16* __restrict__ A,
                                               const u16* __restrict__ B,
                                               const float* __restrict__ bias,
                                               void* __restrict__ Cout,
                                               int M, int N, int K, int nbx) {
  __shared__ u16 As[128 * 64];
  __shared__ u16 Bs[128 * 64];
  const int t = threadIdx.x;
  const int lane = t & 63;
  const int wave = t >> 6;
  const int l15 = lane & 15, l4 = lane >> 4;
  const int wm = (wave >> 1) * 64, wn = (wave & 1) * 64;

  const int nwg = gridDim.x;
  const int lg = (blockIdx.x & 7) * (nwg >> 3) + (blockIdx.x >> 3);
  const int m0 = (lg / nbx) * 128, n0 = (lg % nbx) * 128;

  const u16* gA[4];
  const u16* gB[4];
  u16* lA[4];
  u16* lB[4];
  #pragma unroll
  for (int i = 0; i < 4; ++i) {
    const int c = i * 256 + t;
    const int row = c >> 3;
    const int col = ((c & 7) ^ (row & 7)) * 8;
    gA[i] = A + (size_t)(m0 + row) * K + col;
    gB[i] = B + (size_t)(n0 + row) * K + col;
    lA[i] = &As[c * 8];
    lB[i] = &Bs[c * 8];
  }

  int aoff[4][2], boff[4][2];
  #pragma unroll
  for (int i = 0; i < 4; ++i)
    #pragma unroll
    for (int kk = 0; kk < 2; ++kk) {
      aoff[i][kk] = (wm + i * 16 + l15) * 64 + ((kk * 4 + l4) ^ (l15 & 7)) * 8;
      boff[i][kk] = (wn + i * 16 + l15) * 64 + ((kk * 4 + l4) ^ (l15 & 7)) * 8;
    }

  f32x4 acc[4][4] = {};

  const int nk = K >> 6;
  for (int kt = 0; kt < nk; ++kt) {
    const int k0 = kt << 6;
    #pragma unroll
    for (int i = 0; i < 4; ++i) gload_lds16(gA[i] + k0, lA[i]);
    #pragma unroll
    for (int i = 0; i < 4; ++i) gload_lds16(gB[i] + k0, lB[i]);
    __syncthreads();
    bf16x8 af[4][2], bfr[4][2];
    #pragma unroll
    for (int i = 0; i < 4; ++i)
      #pragma unroll
      for (int kk = 0; kk < 2; ++kk) {
        af[i][kk]  = *reinterpret_cast<const bf16x8*>(&As[aoff[i][kk]]);
        bfr[i][kk] = *reinterpret_cast<const bf16x8*>(&Bs[boff[i][kk]]);
      }
    __builtin_amdgcn_s_setprio(1);
    #pragma unroll
    for (int kk = 0; kk < 2; ++kk)
      #pragma unroll
      for (int i = 0; i < 4; ++i)
        #pragma unroll
        for (int j = 0; j < 4; ++j)
          acc[i][j] = __builtin_amdgcn_mfma_f32_16x16x32_bf16(af[i][kk], bfr[j][kk],
                                                              acc[i][j], 0, 0, 0);
    __builtin_amdgcn_s_setprio(0);
    __syncthreads();
  }

  #pragma unroll
  for (int i = 0; i < 4; ++i) {
    #pragma unroll
    for (int j = 0; j < 4; ++j) {
      const int col = n0 + wn + j * 16 + l15;
      const float bv = bias[col];
      const int rowb = m0 + wm + i * 16 + l4 * 4;
      #pragma unroll
      for (int r = 0; r < 4; ++r) {
        float v = acc[i][j][r] + bv;
        if (OUT_F32)
          reinterpret_cast<float*>(Cout)[(size_t)(rowb + r) * N + col] = v;
        else
          reinterpret_cast<u16*>(Cout)[(size_t)(rowb + r) * N + col] = bf16_bits(v);
      }
    }
  }
}

// ---------------- RoPE + scatter to (H, S, 96) padded, q pre-scaled by 1/sqrt(D) -------
__global__ __launch_bounds__(256) void rope_scatter(const u16* __restrict__ qkv,
                                                    const float* __restrict__ cosb,
                                                    const float* __restrict__ sinb,
                                                    u16* __restrict__ qp,
                                                    u16* __restrict__ kp) {
  const int t = threadIdx.x;
  const int sl = t >> 6;
  const int p = t & 63;
  const int s = blockIdx.x * 4 + sl;
  const int h = blockIdx.y;
  const size_t ib = (size_t)s * QKV_N + h * HD;
  const size_t ob = ((size_t)h * S_LEN + s) * HDP;
  if (p < 40) {
    const float scale = 0.1118033988749895f;  // 1/sqrt(80)
    float q1 = bf16_to_f(qkv[ib + p]);
    float q2 = bf16_to_f(qkv[ib + 40 + p]);
    float k1 = bf16_to_f(qkv[ib + E_DIM + p]);
    float k2 = bf16_to_f(qkv[ib + E_DIM + 40 + p]);
    float c1 = cosb[(size_t)s * HD + p],      s1 = sinb[(size_t)s * HD + p];
    float c2 = cosb[(size_t)s * HD + 40 + p], s2 = sinb[(size_t)s * HD + 40 + p];
    qp[ob + p]      = bf16_bits((q1 * c1 - q2 * s1) * scale);
    qp[ob + 40 + p] = bf16_bits((q2 * c2 + q1 * s2) * scale);
    kp[ob + p]      = bf16_bits(k1 * c1 - k2 * s1);
    kp[ob + 40 + p] = bf16_bits(k2 * c2 + k1 * s2);
  } else if (p < 48) {
    const int pd = HD + (p - 40) * 2;
    qp[ob + pd] = 0; qp[ob + pd + 1] = 0;
    kp[ob + pd] = 0; kp[ob + pd + 1] = 0;
  }
}

// ---------------- V transpose to (H, 80, S) ----------------
__global__ __launch_bounds__(256) void v_transpose(const u16* __restrict__ qkv,
                                                   u16* __restrict__ vt) {
  const int idx = blockIdx.x * 256 + threadIdx.x;
  const int d = idx % HD;
  const int h = (idx / HD) % NH;
  const int sb = idx / (HD * NH);
  const int s0 = sb * 8;
  if (s0 >= S_LEN) return;
  u16 b[8];
  #pragma unroll
  for (int j = 0; j < 8; ++j)
    b[j] = qkv[(size_t)(s0 + j) * QKV_N + 2 * E_DIM + h * HD + d];
  uint4 pk;
  pk.x = b[0] | ((unsigned)b[1] << 16);
  pk.y = b[2] | ((unsigned)b[3] << 16);
  pk.z = b[4] | ((unsigned)b[5] << 16);
  pk.w = b[6] | ((unsigned)b[7] << 16);
  *reinterpret_cast<uint4*>(&vt[((size_t)h * HD + d) * S_LEN + s0]) = pk;
}

// ---------------- segment-local flash attention, swapped-operand layout ----------
// grid 768 = 16 heads x 48 q-blocks(64). 4 waves; wave owns 16 q rows.
// QK^T computed as mfma(K,Q) -> S[k][q]: q on lanes (l15), k in regs (f*16+l4*4+r).
// Softmax stats per-lane scalars. PV computed as mfma(V^T, P^T) -> O^T[d][q].
__global__ __launch_bounds__(256) void attn_fwd(const u16* __restrict__ qp,
                                                const u16* __restrict__ kp,
                                                const u16* __restrict__ vt,
                                                const int* __restrict__ cu, int ncu,
                                                u16* __restrict__ ao) {
  __shared__ u16 Ks[2][64][104];  // 64x96 K tile, +8 u16 pad
  __shared__ u16 Pl[4][16][72];   // per-wave P^T-staging [q][k], XOR-swizzled 16B chunks

  const int lg = ((blockIdx.x & 7) * 96) + (blockIdx.x >> 3);
  const int h = lg / 48;
  const int q0 = (lg % 48) * 64;

  const int t = threadIdx.x;
  const int wave = t >> 6;
  const int lane = t & 63;
  const int l15 = lane & 15, l4 = lane >> 4;
  const int qr = q0 + wave * 16;

  int lo = 0, hi = S_LEN;
  for (int i = 0; i + 1 < ncu; ++i) {
    int a = cu[i], b = cu[i + 1];
    if (q0 >= a && q0 < b) { lo = a; hi = b; }
  }
  const int nt = (hi - lo + 63) >> 6;

  const u16* qh = qp + (size_t)h * S_LEN * HDP;
  const u16* kh = kp + (size_t)h * S_LEN * HDP;
  const u16* vh = vt + (size_t)h * HD * S_LEN;

  // Q fragments (B-operand: col=l15 is q, k=l4*8+j)
  bf16x8 qf[3];
  #pragma unroll
  for (int c = 0; c < 3; ++c)
    qf[c] = *reinterpret_cast<const bf16x8*>(&qh[(size_t)(qr + l15) * HDP + c * 32 + l4 * 8]);

  // prologue: stage tile 0 into Ks[0]
  {
    bf16x8 kreg[3];
    #pragma unroll
    for (int i = 0; i < 3; ++i) {
      const int c2 = i * 256 + t;
      const int r = c2 / 12, cc = c2 % 12;
      const int row = imin(lo + r, S_LEN - 1);
      kreg[i] = *reinterpret_cast<const bf16x8*>(&kh[(size_t)row * HDP + cc * 8]);
    }
    #pragma unroll
    for (int i = 0; i < 3; ++i) {
      const int c2 = i * 256 + t;
      const int r = c2 / 12, cc = c2 % 12;
      *reinterpret_cast<bf16x8*>(&Ks[0][r][cc * 8]) = kreg[i];
    }
    __syncthreads();
  }

  f32x4 oacc[5] = {};           // O^T: d = df*16 + l4*4 + r, q = l15
  float mrow = -INFINITY, lrow = 0.f;
  const float L2E = 1.4426950408889634f;

  // kt-invariant swizzled P LDS offsets
  int pwr[4];  // write: per f, b64 at chunk (f*2+(l4>>1))^(l15&7), half l4&1
  #pragma unroll
  for (int f = 0; f < 4; ++f)
    pwr[f] = ((f * 2 + (l4 >> 1)) ^ (l15 & 7)) * 8 + (l4 & 1) * 4;
  int prd[2];  // read: per kc, b128 at chunk (kc*4+l4)^(l15&7)
  #pragma unroll
  for (int kc = 0; kc < 2; ++kc)
    prd[kc] = ((kc * 4 + l4) ^ (l15 & 7)) * 8;

  int cur = 0;
  for (int ti = 0; ti < nt; ++ti) {
    const int kb = lo + ti * 64;
    const int kbL = imin(kb, S_LEN - 64);

    // V loads for this tile (A-operand of PV: rows d=df*16+l15, k contiguous)
    bf16x8 vreg[2][5];
    #pragma unroll
    for (int kc = 0; kc < 2; ++kc)
      #pragma unroll
      for (int df = 0; df < 5; ++df)
        vreg[kc][df] = *reinterpret_cast<const bf16x8*>(
            &vh[(size_t)(df * 16 + l15) * S_LEN + kbL + kc * 32 + l4 * 8]);

    // prefetch next K tile to regs
    const bool more = (ti + 1) < nt;
    bf16x8 kreg[3];
    if (more) {
      const int kb2 = lo + (ti + 1) * 64;
      #pragma unroll
      for (int i = 0; i < 3; ++i) {
        const int c2 = i * 256 + t;
        const int r = c2 / 12, cc = c2 % 12;
        const int row = imin(kb2 + r, S_LEN - 1);
        kreg[i] = *reinterpret_cast<const bf16x8*>(&kh[(size_t)row * HDP + cc * 8]);
      }
    }

    // QK^T swapped: sc[f] = S[k = f*16 + l4*4 + r][q = l15]
    f32x4 sc[4];
    #pragma unroll
    for (int f = 0; f < 4; ++f) { f32x4 z = {0.f, 0.f, 0.f, 0.f}; sc[f] = z; }
    __builtin_amdgcn_s_setprio(1);
    #pragma unroll
    for (int f = 0; f < 4; ++f)
      #pragma unroll
      for (int c = 0; c < 3; ++c) {
        bf16x8 kf = *reinterpret_cast<const bf16x8*>(&Ks[cur][f * 16 + l15][c * 32 + l4 * 8]);
        sc[f] = __builtin_amdgcn_mfma_f32_16x16x32_bf16(kf, qf[c], sc[f], 0, 0, 0);
      }
    __builtin_amdgcn_s_setprio(0);

    // mask (slow path never taken for 64-multiple segments)
    if (kb + 64 > hi) {
      #pragma unroll
      for (int f = 0; f < 4; ++f)
        #pragma unroll
        for (int r = 0; r < 4; ++r)
          if (kb + f * 16 + l4 * 4 + r >= hi) sc[f][r] = -INFINITY;
    }

    // per-lane (per-q) max over 16 in-reg k values + 2 shuffles across l4
    float tm = -INFINITY;
    #pragma unroll
    for (int f = 0; f < 4; ++f)
      #pragma unroll
      for (int r = 0; r < 4; ++r) tm = fmaxf(tm, sc[f][r]);
    tm = fmaxf(tm, __shfl_xor(tm, 16, 64));
    tm = fmaxf(tm, __shfl_xor(tm, 32, 64));

    // defer-max (T13): rescale only when max grew by > 8
    if (__any(tm > mrow + 8.f)) {
      float mn = fmaxf(mrow, tm);
      float corr = exp2f((mrow - mn) * L2E);
      mrow = mn;
      lrow *= corr;
      #pragma unroll
      for (int df = 0; df < 5; ++df)
        #pragma unroll
        for (int r = 0; r < 4; ++r) oacc[df][r] *= corr;
    }

    // P = exp2((S-m)*log2e); in-lane partial sum; pack pairs; 4x ds_write_b64
    float rs = 0.f;
    #pragma unroll
    for (int f = 0; f < 4; ++f) {
      float p0 = exp2f((sc[f][0] - mrow) * L2E);
      float p1 = exp2f((sc[f][1] - mrow) * L2E);
      float p2 = exp2f((sc[f][2] - mrow) * L2E);
      float p3 = exp2f((sc[f][3] - mrow) * L2E);
      rs += (p0 + p1) + (p2 + p3);
      uint2 w;
      w.x = (u32)bf16_bits(p0) | ((u32)bf16_bits(p1) << 16);
      w.y = (u32)bf16_bits(p2) | ((u32)bf16_bits(p3) << 16);
      *reinterpret_cast<uint2*>(&Pl[wave][l15][pwr[f]]) = w;
    }
    rs += __shfl_xor(rs, 16, 64);
    rs += __shfl_xor(rs, 32, 64);
    lrow += rs;

    asm volatile("s_waitcnt lgkmcnt(0)" ::: "memory");  // own-wave P writes visible

    // PV swapped: oacc[df] += mfma(A=V^T frag, B=P^T frag)
    __builtin_amdgcn_s_setprio(1);
    #pragma unroll
    for (int kc = 0; kc < 2; ++kc) {
      bf16x8 pf = *reinterpret_cast<const bf16x8*>(&Pl[wave][l15][prd[kc]]);
      #pragma unroll
      for (int df = 0; df < 5; ++df)
        oacc[df] = __builtin_amdgcn_mfma_f32_16x16x32_bf16(vreg[kc][df], pf, oacc[df], 0, 0, 0);
    }
    __builtin_amdgcn_s_setprio(0);

    // write next K tile into the other buffer, one barrier per tile
    if (more) {
      #pragma unroll
      for (int i = 0; i < 3; ++i) {
        const int c2 = i * 256 + t;
        const int r = c2 / 12, cc = c2 % 12;
        *reinterpret_cast<bf16x8*>(&Ks[cur ^ 1][r][cc * 8]) = kreg[i];
      }
    }
    __syncthreads();
    cur ^= 1;
  }

  // epilogue: O^T[d][q] -> ao[q][h*HD+d]; lrow is per-lane (q = l15)
  const float inv = 1.0f / lrow;
  #pragma unroll
  for (int df = 0; df < 5; ++df) {
    ushort4 o;
    o.x = bf16_bits(oacc[df][0] * inv);
    o.y = bf16_bits(oacc[df][1] * inv);
    o.z = bf16_bits(oacc[df][2] * inv);
    o.w = bf16_bits(oacc[df][3] * inv);
    *reinterpret_cast<ushort4*>(
        &ao[(size_t)(qr + l15) * E_DIM + h * HD + df * 16 + l4 * 4]) = o;
  }
}

// ---------------- host launch ----------------
extern "C" void kernel_launch(void* const* d_in, const int* in_sizes, int n_in,
                              void* d_out, int out_size, void* d_ws, size_t ws_size,
                              hipStream_t stream) {
  const float* x      = (const float*)d_in[0];
  const int*   cu     = (const int*)d_in[1];
  const float* cosb   = (const float*)d_in[2];
  const float* sinb   = (const float*)d_in[3];
  const float* qkv_w  = (const float*)d_in[4];
  const float* qkv_b  = (const float*)d_in[5];
  const float* proj_w = (const float*)d_in[6];
  const float* proj_b = (const float*)d_in[7];
  float* out = (float*)d_out;

  u16* xb     = (u16*)d_ws;
  u16* wqkvb  = xb     + (size_t)S_LEN * E_DIM;
  u16* wprojb = wqkvb  + (size_t)3 * E_DIM * E_DIM;
  u16* qkv    = wprojb + (size_t)E_DIM * E_DIM;
  u16* qp     = qkv    + (size_t)S_LEN * QKV_N;
  u16* kp     = qp     + (size_t)NH * S_LEN * HDP;
  u16* vt     = kp     + (size_t)NH * S_LEN * HDP;
  u16* attn   = vt     + (size_t)NH * HD * S_LEN;

  const int nf4 = XB_F4 + WQKV_F4 + WPROJ_F4;
  f32_to_bf16_3<<<nf4 / 256, 256, 0, stream>>>(x, qkv_w, proj_w, xb);

  gemm_nt<0><<<(QKV_N / 128) * (S_LEN / 128), 256, 0, stream>>>(
      xb, wqkvb, qkv_b, qkv, S_LEN, QKV_N, E_DIM, QKV_N / 128);

  rope_scatter<<<dim3(S_LEN / 4, NH), 256, 0, stream>>>(qkv, cosb, sinb, qp, kp);
  v_transpose<<<(NH * HD * (S_LEN / 8)) / 256, 256, 0, stream>>>(qkv, vt);

  attn_fwd<<<NH * (S_LEN / 64), 256, 0, stream>>>(qp, kp, vt, cu, in_sizes[1], attn);

  gemm_nt<1><<<(E_DIM / 128) * (S_LEN / 128), 256, 0, stream>>>(
      attn, wprojb, proj_b, out, S_LEN, E_DIM, E_DIM, E_DIM / 128);
}